// Round 4
// baseline (151.092 us; speedup 1.0000x reference)
//
#include <hip/hip_runtime.h>

// StackedLinear (LSQ-quantized, 8 classes x [32 x 1024]), B=8192.
// out[b,o] = alpha[c,o] * sum_i w_int[c,o,i] * x[b,i] + bias[c,o],  c = idx[b]
// w_int = rint(clip(w/alpha,-128,127)) in [-128,127] -> exact in bf16.
//
// R4: 2 graph nodes (was 3). Bucketing moved to ONE 1024-thread block with a
// deterministic packed-histogram + shuffle-scan sort (no global atomics, no
// memset needed). gemm gets an early-exit before B-fragment preload.
//
// Nodes: 1. prep (64 quant blocks x 4 rows + 1 bucket block)
//        2. gemm (split-K=8, no LDS, no barriers, atomicAdd epilogue)

#define IN_F   1024
#define OUT_F  32
#define NCLS   8
#define NB     8192
#define KSPLIT 8
#define KCH    (IN_F / KSPLIT)   // 128
#define GRIDX  40                // m-tile wave-slots: 80 per (c,kq); grid-stride

typedef __attribute__((ext_vector_type(8))) __bf16 bf16x8;
typedef __attribute__((ext_vector_type(4))) float  f32x4;

__device__ __forceinline__ unsigned short f2bf(float f) {
    unsigned int u = __builtin_bit_cast(unsigned int, f);
    u += 0x7FFFu + ((u >> 16) & 1u);
    return (unsigned short)(u >> 16);
}

__device__ __forceinline__ bf16x8 pack8(float4 v0, float4 v1) {
    union { unsigned short u[8]; bf16x8 v; } r;
    r.u[0] = f2bf(v0.x); r.u[1] = f2bf(v0.y); r.u[2] = f2bf(v0.z); r.u[3] = f2bf(v0.w);
    r.u[4] = f2bf(v1.x); r.u[5] = f2bf(v1.y); r.u[6] = f2bf(v1.z); r.u[7] = f2bf(v1.w);
    return r.v;
}

// ---------------------------------------------------------------------------
// Prep. Blocks 0..63 (1024 thr): quantize 4 weight rows each -> bf16 wq + alf.
// Block 64 (1024 thr): deterministic bucket sort of 8192 samples by class
// (8/thread), bias-init of out, counts write. No global atomics.
__global__ __launch_bounds__(1024) void prep_kernel(
    const float* __restrict__ weight, const float* __restrict__ law,
    const unsigned int* __restrict__ lsw, const float* __restrict__ bias,
    float* __restrict__ alf, unsigned short* __restrict__ wq,
    int* __restrict__ counts, unsigned short* __restrict__ buckets,
    float* __restrict__ out)
{
    int t = threadIdx.x;
    if (blockIdx.x < 64) {
        // ---- quantize: 4 rows per block, 256 threads per row (float4 each)
        int row = blockIdx.x * 4 + (t >> 8);
        int c4  = t & 255;
        float a = expf(law[row]);
        if (c4 == 0) alf[row] = a;
        float4 v = ((const float4*)(weight + (size_t)row * IN_F))[c4];
        ushort4 p;
        p.x = f2bf(rintf(fminf(fmaxf(v.x / a, -128.f), 127.f)));
        p.y = f2bf(rintf(fminf(fmaxf(v.y / a, -128.f), 127.f)));
        p.z = f2bf(rintf(fminf(fmaxf(v.z / a, -128.f), 127.f)));
        p.w = f2bf(rintf(fminf(fmaxf(v.w / a, -128.f), 127.f)));
        ((ushort4*)(wq + (size_t)row * IN_F))[c4] = p;
        return;
    }
    // ---- bucket block: 1024 threads = 16 waves, 8 samples/thread
    int lane = t & 63, wv = t >> 6;
    __shared__ int s_is64;
    __shared__ unsigned int wtot[16][4];
    __shared__ unsigned int wbase[16][4];
    if (t == 0) s_is64 = 1;
    __syncthreads();
    // int64-vs-int32 width detect: values 0..7 => int64 has all odd 32-bit
    // words zero; int32 random 0..7 => P(all 4096 zero) = 8^-4096.
    int bad = 0;
    #pragma unroll
    for (int j = 0; j < 4; ++j) bad |= (lsw[2 * (j * 1024 + t) + 1] != 0u);
    if (bad) atomicAnd(&s_is64, 0);
    __syncthreads();
    int is64 = s_is64;
    // read classes (coalesced), pack 8x 4-bit; per-class counts packed as
    // 8 classes x 16-bit fields in 4 uints (max 8192 per field: no overflow)
    unsigned int cpack = 0;
    unsigned int cnt[4] = {0, 0, 0, 0};
    #pragma unroll
    for (int j = 0; j < 8; ++j) {
        int b = j * 1024 + t;
        int c = is64 ? (int)lsw[2 * b] : (int)lsw[b];
        cpack |= (unsigned int)c << (j * 4);
        cnt[c >> 1] += 1u << ((c & 1) * 16);
    }
    // wave inclusive scan (shuffle butterfly up)
    unsigned int inc[4] = {cnt[0], cnt[1], cnt[2], cnt[3]};
    #pragma unroll
    for (int d = 1; d < 64; d <<= 1) {
        unsigned int o0 = __shfl_up(inc[0], d), o1 = __shfl_up(inc[1], d);
        unsigned int o2 = __shfl_up(inc[2], d), o3 = __shfl_up(inc[3], d);
        if (lane >= d) { inc[0] += o0; inc[1] += o1; inc[2] += o2; inc[3] += o3; }
    }
    if (lane == 63) {
        wtot[wv][0] = inc[0]; wtot[wv][1] = inc[1];
        wtot[wv][2] = inc[2]; wtot[wv][3] = inc[3];
    }
    __syncthreads();
    if (t < 16) {   // exclusive scan over 16 wave totals (serial: 16 iters, trivial)
        unsigned int b0 = 0, b1 = 0, b2 = 0, b3 = 0;
        for (int w2 = 0; w2 < t; ++w2) {
            b0 += wtot[w2][0]; b1 += wtot[w2][1];
            b2 += wtot[w2][2]; b3 += wtot[w2][3];
        }
        wbase[t][0] = b0; wbase[t][1] = b1; wbase[t][2] = b2; wbase[t][3] = b3;
        if (t == 15) {
            unsigned int tt[4] = {b0 + wtot[15][0], b1 + wtot[15][1],
                                  b2 + wtot[15][2], b3 + wtot[15][3]};
            #pragma unroll
            for (int c = 0; c < NCLS; ++c)
                counts[c] = (int)((tt[c >> 1] >> ((c & 1) * 16)) & 0xFFFFu);
        }
    }
    __syncthreads();
    // scatter + bias-init; pos = wave base + lane-exclusive, bump as we go
    unsigned int pos[4];
    #pragma unroll
    for (int f = 0; f < 4; ++f) pos[f] = wbase[wv][f] + (inc[f] - cnt[f]);
    #pragma unroll
    for (int j = 0; j < 8; ++j) {
        int b = j * 1024 + t;
        int c = (cpack >> (j * 4)) & 7;
        unsigned int p = (pos[c >> 1] >> ((c & 1) * 16)) & 0xFFFFu;
        pos[c >> 1] += 1u << ((c & 1) * 16);
        buckets[c * NB + p] = (unsigned short)b;
        const float4* bb = (const float4*)(bias + c * OUT_F);
        float4* ob = (float4*)(out + (size_t)b * OUT_F);
        #pragma unroll
        for (int i = 0; i < OUT_F / 4; ++i) ob[i] = bb[i];
    }
}

// ---------------------------------------------------------------------------
// Split-K GEMM, no LDS, no barriers. Block = 128 thr = 2 waves; each wave:
// m-tile of 16 samples, both n-halves (2 accs), K-chunk of 128.
// MFMA 16x16x32 bf16 layouts (verified R1-R3): A[m=lane&15][k=q*8+j],
// B^T[n=lane&15][k=q*8+j], D: n=lane&15, m=q*4+reg.
__global__ __launch_bounds__(128) void gemm_kernel(
    const float* __restrict__ x, const float* __restrict__ alf,
    const unsigned short* __restrict__ wq,
    const int* __restrict__ counts, const unsigned short* __restrict__ buckets,
    float* __restrict__ out)
{
    int c  = blockIdx.y;
    int kq = blockIdx.z;
    int cnt = counts[c];
    int ntiles = (cnt + 15) >> 4;
    if ((int)blockIdx.x * 2 >= ntiles) return;   // skip B-preload for idle blocks
    int t = threadIdx.x;
    int wave = t >> 6, lane = t & 63;
    int fr = lane & 15, fq = lane >> 4;
    int k0 = kq * KCH;

    // B fragments, both n-halves, 4 k-steps, in VGPRs (L2-hot loads)
    const unsigned short* wrow0 = wq + (size_t)(c * OUT_F + fr) * IN_F + k0 + fq * 8;
    const unsigned short* wrow1 = wrow0 + 16 * IN_F;
    bf16x8 Bf0[KCH / 32], Bf1[KCH / 32];
    #pragma unroll
    for (int kk = 0; kk < KCH / 32; ++kk) {
        Bf0[kk] = *(const bf16x8*)(wrow0 + kk * 32);
        Bf1[kk] = *(const bf16x8*)(wrow1 + kk * 32);
    }
    float a0 = alf[c * OUT_F + fr];
    float a1 = alf[c * OUT_F + 16 + fr];

    for (int tile = blockIdx.x * 2 + wave; tile < ntiles; tile += GRIDX * 2) {
        int start = tile * 16;
        int nvalid = min(16, cnt - start);
        int j = min(fr, nvalid - 1);                 // clamp: dup valid row
        int srow = (int)buckets[c * NB + start + j]; // this lane's m-row sample
        const float* xr = x + (size_t)srow * IN_F + k0 + fq * 8;
        f32x4 acc0 = {0.f, 0.f, 0.f, 0.f};
        f32x4 acc1 = {0.f, 0.f, 0.f, 0.f};
        #pragma unroll
        for (int kk = 0; kk < KCH / 32; ++kk) {
            float4 v0 = *(const float4*)(xr + kk * 32);
            float4 v1 = *(const float4*)(xr + kk * 32 + 4);
            bf16x8 a = pack8(v0, v1);
            acc0 = __builtin_amdgcn_mfma_f32_16x16x32_bf16(a, Bf0[kk], acc0, 0, 0, 0);
            acc1 = __builtin_amdgcn_mfma_f32_16x16x32_bf16(a, Bf1[kk], acc1, 0, 0, 0);
        }
        #pragma unroll
        for (int reg = 0; reg < 4; ++reg) {
            int m = fq * 4 + reg;
            int sr = __shfl(srow, m);                // lane m holds row m's id
            if (m < nvalid) {
                atomicAdd(&out[(size_t)sr * OUT_F + fr],      acc0[reg] * a0);
                atomicAdd(&out[(size_t)sr * OUT_F + 16 + fr], acc1[reg] * a1);
            }
        }
    }
}

// ---------------------------------------------------------------------------
extern "C" void kernel_launch(void* const* d_in, const int* in_sizes, int n_in,
                              void* d_out, int out_size, void* d_ws, size_t ws_size,
                              hipStream_t stream)
{
    (void)in_sizes; (void)n_in; (void)out_size; (void)ws_size;
    const float*        x      = (const float*)d_in[0];
    const unsigned int* ls     = (const unsigned int*)d_in[1];
    const float*        weight = (const float*)d_in[2];
    const float*        bias   = (const float*)d_in[3];
    const float*        law    = (const float*)d_in[4];
    float*              out    = (float*)d_out;

    char* ws = (char*)d_ws;
    int*            counts  = (int*)ws;                                   // 32 B
    float*          alf     = (float*)(ws + 64);                          // 1 KB
    unsigned short* wq      = (unsigned short*)(ws + 64 + 1024);          // 512 KB
    unsigned short* buckets = (unsigned short*)(ws + 64 + 1024 + 524288); // 128 KB

    prep_kernel<<<65, 1024, 0, stream>>>(
        weight, law, ls, bias, alf, wq, counts, buckets, out);
    gemm_kernel<<<dim3(GRIDX, NCLS, KSPLIT), 128, 0, stream>>>(
        x, alf, wq, counts, buckets, out);
}

// Round 5
// 92.914 us; speedup vs baseline: 1.6261x; 1.6261x over previous
//
#include <hip/hip_runtime.h>

// StackedLinear (LSQ-quantized, 8 classes x [32 x 1024]), B=8192.
// out[b,o] = alpha[c,o] * sum_i w_int[c,o,i] * x[b,i] + bias[c,o],  c = idx[b]
// w_int = rint(clip(w/alpha,-128,127)) in [-128,127] -> exact in bf16.
//
// R5: fix R4's 66us prep regression (bias-init of 1 MB was inside the SINGLE
// sort block -> one-CU write bottleneck). Now: 64 quant blocks + 32 coalesced
// bias-init blocks + 1 sort-only block. Still 2 graph nodes.
//
// Nodes: 1. prep (quant W | bias-init out | bucket sort)
//        2. gemm (split-K=8, no LDS, no barriers, atomicAdd epilogue)

#define IN_F   1024
#define OUT_F  32
#define NCLS   8
#define NB     8192
#define KSPLIT 8
#define KCH    (IN_F / KSPLIT)   // 128
#define GRIDX  40                // m-tile wave-slots: 80 per (c,kq); grid-stride

typedef __attribute__((ext_vector_type(8))) __bf16 bf16x8;
typedef __attribute__((ext_vector_type(4))) float  f32x4;

__device__ __forceinline__ unsigned short f2bf(float f) {
    unsigned int u = __builtin_bit_cast(unsigned int, f);
    u += 0x7FFFu + ((u >> 16) & 1u);
    return (unsigned short)(u >> 16);
}

__device__ __forceinline__ bf16x8 pack8(float4 v0, float4 v1) {
    union { unsigned short u[8]; bf16x8 v; } r;
    r.u[0] = f2bf(v0.x); r.u[1] = f2bf(v0.y); r.u[2] = f2bf(v0.z); r.u[3] = f2bf(v0.w);
    r.u[4] = f2bf(v1.x); r.u[5] = f2bf(v1.y); r.u[6] = f2bf(v1.z); r.u[7] = f2bf(v1.w);
    return r.v;
}

// ---------------------------------------------------------------------------
// Prep, 97 blocks x 1024 threads:
//   blocks 0..63 : quantize 4 weight rows each -> bf16 wq + alf
//   blocks 64..95: out[b] = bias[class(b)] for 256 rows each, coalesced
//   block  96    : deterministic bucket sort (histogram + shuffle scan +
//                  16 KB scatter), counts write. No global atomics.
__global__ __launch_bounds__(1024) void prep_kernel(
    const float* __restrict__ weight, const float* __restrict__ law,
    const unsigned int* __restrict__ lsw, const float* __restrict__ bias,
    float* __restrict__ alf, unsigned short* __restrict__ wq,
    int* __restrict__ counts, unsigned short* __restrict__ buckets,
    float* __restrict__ out)
{
    int t = threadIdx.x;
    if (blockIdx.x < 64) {
        // ---- quantize: 4 rows per block, 256 threads per row (float4 each)
        int row = blockIdx.x * 4 + (t >> 8);
        int c4  = t & 255;
        float a = expf(law[row]);
        if (c4 == 0) alf[row] = a;
        float4 v = ((const float4*)(weight + (size_t)row * IN_F))[c4];
        ushort4 p;
        p.x = f2bf(rintf(fminf(fmaxf(v.x / a, -128.f), 127.f)));
        p.y = f2bf(rintf(fminf(fmaxf(v.y / a, -128.f), 127.f)));
        p.z = f2bf(rintf(fminf(fmaxf(v.z / a, -128.f), 127.f)));
        p.w = f2bf(rintf(fminf(fmaxf(v.w / a, -128.f), 127.f)));
        ((ushort4*)(wq + (size_t)row * IN_F))[c4] = p;
        return;
    }
    if (blockIdx.x < 96) {
        // ---- bias-init: 256 out rows per block, 8 threads/row, coalesced.
        // Width detect on this block's 256 odd words: int64 (vals 0..7) =>
        // all zero; int32 => P(all zero) = 8^-256 ~ 0.
        int base = (int)(blockIdx.x - 64) * 256;
        __shared__ int s_is64b;
        if (t == 0) s_is64b = 1;
        __syncthreads();
        if (t < 256 && lsw[2 * (base + t) + 1] != 0u) atomicAnd(&s_is64b, 0);
        __syncthreads();
        int is64 = s_is64b;
        #pragma unroll
        for (int p = 0; p < 2; ++p) {
            int row  = base + p * 128 + (t >> 3);
            int quad = t & 7;
            int c = is64 ? (int)lsw[2 * row] : (int)lsw[row];
            ((float4*)(out + (size_t)row * OUT_F))[quad] =
                ((const float4*)(bias + c * OUT_F))[quad];
        }
        return;
    }
    // ---- sort block: 1024 threads = 16 waves, 8 samples/thread
    int lane = t & 63, wv = t >> 6;
    __shared__ int s_is64;
    __shared__ unsigned int wtot[16][4];
    __shared__ unsigned int wbase[16][4];
    if (t == 0) s_is64 = 1;
    __syncthreads();
    int bad = 0;
    #pragma unroll
    for (int j = 0; j < 4; ++j) bad |= (lsw[2 * (j * 1024 + t) + 1] != 0u);
    if (bad) atomicAnd(&s_is64, 0);
    __syncthreads();
    int is64 = s_is64;
    // coalesced class reads; 8x 4-bit pack; counts as 8x16-bit packed fields
    unsigned int cpack = 0;
    unsigned int cnt[4] = {0, 0, 0, 0};
    #pragma unroll
    for (int j = 0; j < 8; ++j) {
        int b = j * 1024 + t;
        int c = is64 ? (int)lsw[2 * b] : (int)lsw[b];
        cpack |= (unsigned int)c << (j * 4);
        cnt[c >> 1] += 1u << ((c & 1) * 16);
    }
    unsigned int inc[4] = {cnt[0], cnt[1], cnt[2], cnt[3]};
    #pragma unroll
    for (int d = 1; d < 64; d <<= 1) {
        unsigned int o0 = __shfl_up(inc[0], d), o1 = __shfl_up(inc[1], d);
        unsigned int o2 = __shfl_up(inc[2], d), o3 = __shfl_up(inc[3], d);
        if (lane >= d) { inc[0] += o0; inc[1] += o1; inc[2] += o2; inc[3] += o3; }
    }
    if (lane == 63) {
        wtot[wv][0] = inc[0]; wtot[wv][1] = inc[1];
        wtot[wv][2] = inc[2]; wtot[wv][3] = inc[3];
    }
    __syncthreads();
    if (t < 16) {   // serial exclusive scan over 16 wave totals
        unsigned int b0 = 0, b1 = 0, b2 = 0, b3 = 0;
        for (int w2 = 0; w2 < t; ++w2) {
            b0 += wtot[w2][0]; b1 += wtot[w2][1];
            b2 += wtot[w2][2]; b3 += wtot[w2][3];
        }
        wbase[t][0] = b0; wbase[t][1] = b1; wbase[t][2] = b2; wbase[t][3] = b3;
        if (t == 15) {
            unsigned int tt[4] = {b0 + wtot[15][0], b1 + wtot[15][1],
                                  b2 + wtot[15][2], b3 + wtot[15][3]};
            #pragma unroll
            for (int c = 0; c < NCLS; ++c)
                counts[c] = (int)((tt[c >> 1] >> ((c & 1) * 16)) & 0xFFFFu);
        }
    }
    __syncthreads();
    unsigned int pos[4];
    #pragma unroll
    for (int f = 0; f < 4; ++f) pos[f] = wbase[wv][f] + (inc[f] - cnt[f]);
    #pragma unroll
    for (int j = 0; j < 8; ++j) {
        int b = j * 1024 + t;
        int c = (cpack >> (j * 4)) & 7;
        unsigned int p = (pos[c >> 1] >> ((c & 1) * 16)) & 0xFFFFu;
        pos[c >> 1] += 1u << ((c & 1) * 16);
        buckets[c * NB + p] = (unsigned short)b;
    }
}

// ---------------------------------------------------------------------------
// Split-K GEMM, no LDS, no barriers. Block = 128 thr = 2 waves; each wave:
// m-tile of 16 samples, both n-halves (2 accs), K-chunk of 128.
// MFMA 16x16x32 bf16 layouts (verified R1-R4): A[m=lane&15][k=q*8+j],
// B^T[n=lane&15][k=q*8+j], D: n=lane&15, m=q*4+reg.
__global__ __launch_bounds__(128) void gemm_kernel(
    const float* __restrict__ x, const float* __restrict__ alf,
    const unsigned short* __restrict__ wq,
    const int* __restrict__ counts, const unsigned short* __restrict__ buckets,
    float* __restrict__ out)
{
    int c  = blockIdx.y;
    int kq = blockIdx.z;
    int cnt = counts[c];
    int ntiles = (cnt + 15) >> 4;
    if ((int)blockIdx.x * 2 >= ntiles) return;   // idle: skip B-preload
    int t = threadIdx.x;
    int wave = t >> 6, lane = t & 63;
    int fr = lane & 15, fq = lane >> 4;
    int k0 = kq * KCH;

    const unsigned short* wrow0 = wq + (size_t)(c * OUT_F + fr) * IN_F + k0 + fq * 8;
    const unsigned short* wrow1 = wrow0 + 16 * IN_F;
    bf16x8 Bf0[KCH / 32], Bf1[KCH / 32];
    #pragma unroll
    for (int kk = 0; kk < KCH / 32; ++kk) {
        Bf0[kk] = *(const bf16x8*)(wrow0 + kk * 32);
        Bf1[kk] = *(const bf16x8*)(wrow1 + kk * 32);
    }
    float a0 = alf[c * OUT_F + fr];
    float a1 = alf[c * OUT_F + 16 + fr];

    for (int tile = blockIdx.x * 2 + wave; tile < ntiles; tile += GRIDX * 2) {
        int start = tile * 16;
        int nvalid = min(16, cnt - start);
        int j = min(fr, nvalid - 1);                 // clamp: dup valid row
        int srow = (int)buckets[c * NB + start + j];
        const float* xr = x + (size_t)srow * IN_F + k0 + fq * 8;
        f32x4 acc0 = {0.f, 0.f, 0.f, 0.f};
        f32x4 acc1 = {0.f, 0.f, 0.f, 0.f};
        #pragma unroll
        for (int kk = 0; kk < KCH / 32; ++kk) {
            float4 v0 = *(const float4*)(xr + kk * 32);
            float4 v1 = *(const float4*)(xr + kk * 32 + 4);
            bf16x8 a = pack8(v0, v1);
            acc0 = __builtin_amdgcn_mfma_f32_16x16x32_bf16(a, Bf0[kk], acc0, 0, 0, 0);
            acc1 = __builtin_amdgcn_mfma_f32_16x16x32_bf16(a, Bf1[kk], acc1, 0, 0, 0);
        }
        #pragma unroll
        for (int reg = 0; reg < 4; ++reg) {
            int m = fq * 4 + reg;
            int sr = __shfl(srow, m);                // lane m holds row m's id
            if (m < nvalid) {
                atomicAdd(&out[(size_t)sr * OUT_F + fr],      acc0[reg] * a0);
                atomicAdd(&out[(size_t)sr * OUT_F + 16 + fr], acc1[reg] * a1);
            }
        }
    }
}

// ---------------------------------------------------------------------------
extern "C" void kernel_launch(void* const* d_in, const int* in_sizes, int n_in,
                              void* d_out, int out_size, void* d_ws, size_t ws_size,
                              hipStream_t stream)
{
    (void)in_sizes; (void)n_in; (void)out_size; (void)ws_size;
    const float*        x      = (const float*)d_in[0];
    const unsigned int* ls     = (const unsigned int*)d_in[1];
    const float*        weight = (const float*)d_in[2];
    const float*        bias   = (const float*)d_in[3];
    const float*        law    = (const float*)d_in[4];
    float*              out    = (float*)d_out;

    char* ws = (char*)d_ws;
    int*            counts  = (int*)ws;                                   // 32 B
    float*          alf     = (float*)(ws + 64);                          // 1 KB
    unsigned short* wq      = (unsigned short*)(ws + 64 + 1024);          // 512 KB
    unsigned short* buckets = (unsigned short*)(ws + 64 + 1024 + 524288); // 128 KB

    prep_kernel<<<97, 1024, 0, stream>>>(
        weight, law, ls, bias, alf, wq, counts, buckets, out);
    gemm_kernel<<<dim3(GRIDX, NCLS, KSPLIT), 128, 0, stream>>>(
        x, alf, wq, counts, buckets, out);
}

// Round 6
// 90.616 us; speedup vs baseline: 1.6674x; 1.0254x over previous
//
#include <hip/hip_runtime.h>

// StackedLinear (LSQ-quantized, 8 classes x [32 x 1024]), B=8192.
// out[b,o] = alpha[c,o] * sum_i w_int[c,o,i] * x[b,i] + bias[c,o],  c = idx[b]
// w_int = rint(clip(w/alpha,-128,127)) in [-128,127] -> exact in bf16.
//
// R6: parallelize the bucket sort 8x (one block per class, scalar scan,
// contiguous per-class scatter) -- the last multi-us controllable item.
// Everything else identical to R5 (92.9 us; harness poison/restore floor ~80).
//
// Nodes: 1. prep (64 quant blocks | 32 bias-init blocks | 8 sort blocks)
//        2. gemm (split-K=8, no LDS, no barriers, atomicAdd epilogue)

#define IN_F   1024
#define OUT_F  32
#define NCLS   8
#define NB     8192
#define KSPLIT 8
#define KCH    (IN_F / KSPLIT)   // 128
#define GRIDX  40                // m-tile wave-slots: 80 per (c,kq); grid-stride

typedef __attribute__((ext_vector_type(8))) __bf16 bf16x8;
typedef __attribute__((ext_vector_type(4))) float  f32x4;

__device__ __forceinline__ unsigned short f2bf(float f) {
    unsigned int u = __builtin_bit_cast(unsigned int, f);
    u += 0x7FFFu + ((u >> 16) & 1u);
    return (unsigned short)(u >> 16);
}

__device__ __forceinline__ bf16x8 pack8(float4 v0, float4 v1) {
    union { unsigned short u[8]; bf16x8 v; } r;
    r.u[0] = f2bf(v0.x); r.u[1] = f2bf(v0.y); r.u[2] = f2bf(v0.z); r.u[3] = f2bf(v0.w);
    r.u[4] = f2bf(v1.x); r.u[5] = f2bf(v1.y); r.u[6] = f2bf(v1.z); r.u[7] = f2bf(v1.w);
    return r.v;
}

// ---------------------------------------------------------------------------
// Prep, 104 blocks x 1024 threads:
//   blocks 0..63  : quantize 4 weight rows each -> bf16 wq + alf
//   blocks 64..95 : out[b] = bias[class(b)] for 256 rows each, coalesced
//   blocks 96..103: bucket sort for class (blockIdx.x-96): scalar shuffle
//                   scan over 8 samples/thread, contiguous scatter, counts[c].
//   No global atomics anywhere; int64-vs-int32 width detect per block
//   (int64 vals 0..7 => odd words all zero -> all blocks agree; int32 =>
//   P(false) <= 8^-256 per block).
__global__ __launch_bounds__(1024) void prep_kernel(
    const float* __restrict__ weight, const float* __restrict__ law,
    const unsigned int* __restrict__ lsw, const float* __restrict__ bias,
    float* __restrict__ alf, unsigned short* __restrict__ wq,
    int* __restrict__ counts, unsigned short* __restrict__ buckets,
    float* __restrict__ out)
{
    int t = threadIdx.x;
    if (blockIdx.x < 64) {
        // ---- quantize: 4 rows per block, 256 threads per row (float4 each)
        int row = blockIdx.x * 4 + (t >> 8);
        int c4  = t & 255;
        float a = expf(law[row]);
        if (c4 == 0) alf[row] = a;
        float4 v = ((const float4*)(weight + (size_t)row * IN_F))[c4];
        ushort4 p;
        p.x = f2bf(rintf(fminf(fmaxf(v.x / a, -128.f), 127.f)));
        p.y = f2bf(rintf(fminf(fmaxf(v.y / a, -128.f), 127.f)));
        p.z = f2bf(rintf(fminf(fmaxf(v.z / a, -128.f), 127.f)));
        p.w = f2bf(rintf(fminf(fmaxf(v.w / a, -128.f), 127.f)));
        ((ushort4*)(wq + (size_t)row * IN_F))[c4] = p;
        return;
    }
    if (blockIdx.x < 96) {
        // ---- bias-init: 256 out rows per block, 8 threads/row, coalesced
        int base = (int)(blockIdx.x - 64) * 256;
        __shared__ int s_is64b;
        if (t == 0) s_is64b = 1;
        __syncthreads();
        if (t < 256 && lsw[2 * (base + t) + 1] != 0u) atomicAnd(&s_is64b, 0);
        __syncthreads();
        int is64 = s_is64b;
        #pragma unroll
        for (int p = 0; p < 2; ++p) {
            int row  = base + p * 128 + (t >> 3);
            int quad = t & 7;
            int c = is64 ? (int)lsw[2 * row] : (int)lsw[row];
            ((float4*)(out + (size_t)row * OUT_F))[quad] =
                ((const float4*)(bias + c * OUT_F))[quad];
        }
        return;
    }
    // ---- sort block for class c: 1024 threads = 16 waves, 8 samples/thread
    int c = (int)blockIdx.x - 96;
    int lane = t & 63, wv = t >> 6;
    __shared__ int s_is64;
    __shared__ int wtot[16];
    __shared__ int wbase[16];
    if (t == 0) s_is64 = 1;
    __syncthreads();
    int bad = 0;
    #pragma unroll
    for (int j = 0; j < 4; ++j) bad |= (lsw[2 * (j * 1024 + t) + 1] != 0u);
    if (bad) atomicAnd(&s_is64, 0);
    __syncthreads();
    int is64 = s_is64;
    // match mask for this thread's 8 samples (coalesced reads)
    unsigned int match = 0;
    int cnt = 0;
    #pragma unroll
    for (int j = 0; j < 8; ++j) {
        int b = j * 1024 + t;
        int cl = is64 ? (int)lsw[2 * b] : (int)lsw[b];
        if (cl == c) { match |= 1u << j; ++cnt; }
    }
    // scalar inclusive scan: wave shuffle + cross-wave serial
    int inc = cnt;
    #pragma unroll
    for (int d = 1; d < 64; d <<= 1) {
        int o = __shfl_up(inc, d);
        if (lane >= d) inc += o;
    }
    if (lane == 63) wtot[wv] = inc;
    __syncthreads();
    if (t < 16) {
        int b0 = 0;
        for (int w2 = 0; w2 < t; ++w2) b0 += wtot[w2];
        wbase[t] = b0;
        if (t == 15) counts[c] = b0 + wtot[15];
    }
    __syncthreads();
    int pos = wbase[wv] + inc - cnt;
    unsigned short* bk = buckets + c * NB;
    #pragma unroll
    for (int j = 0; j < 8; ++j) {
        if ((match >> j) & 1u) bk[pos++] = (unsigned short)(j * 1024 + t);
    }
}

// ---------------------------------------------------------------------------
// Split-K GEMM, no LDS, no barriers. Block = 128 thr = 2 waves; each wave:
// m-tile of 16 samples, both n-halves (2 accs), K-chunk of 128.
// MFMA 16x16x32 bf16 layouts (verified R1-R5): A[m=lane&15][k=q*8+j],
// B^T[n=lane&15][k=q*8+j], D: n=lane&15, m=q*4+reg.
__global__ __launch_bounds__(128) void gemm_kernel(
    const float* __restrict__ x, const float* __restrict__ alf,
    const unsigned short* __restrict__ wq,
    const int* __restrict__ counts, const unsigned short* __restrict__ buckets,
    float* __restrict__ out)
{
    int c  = blockIdx.y;
    int kq = blockIdx.z;
    int cnt = counts[c];
    int ntiles = (cnt + 15) >> 4;
    if ((int)blockIdx.x * 2 >= ntiles) return;   // idle: skip B-preload
    int t = threadIdx.x;
    int wave = t >> 6, lane = t & 63;
    int fr = lane & 15, fq = lane >> 4;
    int k0 = kq * KCH;

    const unsigned short* wrow0 = wq + (size_t)(c * OUT_F + fr) * IN_F + k0 + fq * 8;
    const unsigned short* wrow1 = wrow0 + 16 * IN_F;
    bf16x8 Bf0[KCH / 32], Bf1[KCH / 32];
    #pragma unroll
    for (int kk = 0; kk < KCH / 32; ++kk) {
        Bf0[kk] = *(const bf16x8*)(wrow0 + kk * 32);
        Bf1[kk] = *(const bf16x8*)(wrow1 + kk * 32);
    }
    float a0 = alf[c * OUT_F + fr];
    float a1 = alf[c * OUT_F + 16 + fr];

    for (int tile = blockIdx.x * 2 + wave; tile < ntiles; tile += GRIDX * 2) {
        int start = tile * 16;
        int nvalid = min(16, cnt - start);
        int j = min(fr, nvalid - 1);                 // clamp: dup valid row
        int srow = (int)buckets[c * NB + start + j];
        const float* xr = x + (size_t)srow * IN_F + k0 + fq * 8;
        f32x4 acc0 = {0.f, 0.f, 0.f, 0.f};
        f32x4 acc1 = {0.f, 0.f, 0.f, 0.f};
        #pragma unroll
        for (int kk = 0; kk < KCH / 32; ++kk) {
            float4 v0 = *(const float4*)(xr + kk * 32);
            float4 v1 = *(const float4*)(xr + kk * 32 + 4);
            bf16x8 a = pack8(v0, v1);
            acc0 = __builtin_amdgcn_mfma_f32_16x16x32_bf16(a, Bf0[kk], acc0, 0, 0, 0);
            acc1 = __builtin_amdgcn_mfma_f32_16x16x32_bf16(a, Bf1[kk], acc1, 0, 0, 0);
        }
        #pragma unroll
        for (int reg = 0; reg < 4; ++reg) {
            int m = fq * 4 + reg;
            int sr = __shfl(srow, m);                // lane m holds row m's id
            if (m < nvalid) {
                atomicAdd(&out[(size_t)sr * OUT_F + fr],      acc0[reg] * a0);
                atomicAdd(&out[(size_t)sr * OUT_F + 16 + fr], acc1[reg] * a1);
            }
        }
    }
}

// ---------------------------------------------------------------------------
extern "C" void kernel_launch(void* const* d_in, const int* in_sizes, int n_in,
                              void* d_out, int out_size, void* d_ws, size_t ws_size,
                              hipStream_t stream)
{
    (void)in_sizes; (void)n_in; (void)out_size; (void)ws_size;
    const float*        x      = (const float*)d_in[0];
    const unsigned int* ls     = (const unsigned int*)d_in[1];
    const float*        weight = (const float*)d_in[2];
    const float*        bias   = (const float*)d_in[3];
    const float*        law    = (const float*)d_in[4];
    float*              out    = (float*)d_out;

    char* ws = (char*)d_ws;
    int*            counts  = (int*)ws;                                   // 32 B
    float*          alf     = (float*)(ws + 64);                          // 1 KB
    unsigned short* wq      = (unsigned short*)(ws + 64 + 1024);          // 512 KB
    unsigned short* buckets = (unsigned short*)(ws + 64 + 1024 + 524288); // 128 KB

    prep_kernel<<<104, 1024, 0, stream>>>(
        weight, law, ls, bias, alf, wq, counts, buckets, out);
    gemm_kernel<<<dim3(GRIDX, NCLS, KSPLIT), 128, 0, stream>>>(
        x, alf, wq, counts, buckets, out);
}